// Round 1
// baseline (607.970 us; speedup 1.0000x reference)
//
#include <hip/hip_runtime.h>
#include <hip/hip_bf16.h>
#include <float.h>
#include <math.h>

#define KEY_DIM   512
#define VALUE_DIM 128
#define CAPACITY  500000
#define NRET      16
#define NBLK2     1024   // blocks for the similarity kernel

__device__ __forceinline__ float wave_sum(float x) {
#pragma unroll
    for (int s = 32; s > 0; s >>= 1) x += __shfl_xor(x, s);
    return x;
}

// ---------------- Kernel 1a/1b: y[r] = act(dot(W[r,:], x) + b[r]) ----------
// One output row per wave; 4 waves/block; 128 blocks cover 512 rows.
template <bool SILU>
__global__ __launch_bounds__(256) void matvec512(
        const float* __restrict__ W, const float* __restrict__ x,
        const float* __restrict__ b, float* __restrict__ y) {
    const int wid  = threadIdx.x >> 6;
    const int lane = threadIdx.x & 63;
    const int r = blockIdx.x * 4 + wid;          // 0..511

    const float4* Wr = (const float4*)(W + (size_t)r * KEY_DIM);
    const float4* xv = (const float4*)x;

    float4 w0 = Wr[lane], w1 = Wr[lane + 64];
    float4 x0 = xv[lane], x1 = xv[lane + 64];

    float dot = w0.x * x0.x + w0.y * x0.y + w0.z * x0.z + w0.w * x0.w
              + w1.x * x1.x + w1.y * x1.y + w1.z * x1.z + w1.w * x1.w;
    dot = wave_sum(dot);

    if (lane == 0) {
        float v = dot + b[r];
        if (SILU) v = v / (1.0f + expf(-v));     // silu = x*sigmoid(x)
        y[r] = v;
    }
}

// ---------------- Kernel 1c: LayerNorm + l2-normalize -> qn[512] -----------
__global__ __launch_bounds__(512) void ln_l2norm(
        const float* __restrict__ h, const float* __restrict__ gamma,
        const float* __restrict__ beta, float* __restrict__ qn) {
    __shared__ float s1[8], s2[8];
    const int t = threadIdx.x;                   // 512 threads = 8 waves
    const int wid = t >> 6, lane = t & 63;

    float x = h[t];
    float a = x, bb = x * x;
#pragma unroll
    for (int s = 32; s > 0; s >>= 1) { a += __shfl_xor(a, s); bb += __shfl_xor(bb, s); }
    if (lane == 0) { s1[wid] = a; s2[wid] = bb; }
    __syncthreads();

    float suma = 0.f, sumb = 0.f;
#pragma unroll
    for (int i = 0; i < 8; ++i) { suma += s1[i]; sumb += s2[i]; }
    float mu  = suma * (1.0f / KEY_DIM);
    float var = sumb * (1.0f / KEY_DIM) - mu * mu;      // biased, like torch LN
    float ln  = (x - mu) / sqrtf(var + 1e-5f) * gamma[t] + beta[t];

    float c = wave_sum(ln * ln);
    __syncthreads();
    if (lane == 0) s1[wid] = c;
    __syncthreads();
    float ss = 0.f;
#pragma unroll
    for (int i = 0; i < 8; ++i) ss += s1[i];
    float n = fmaxf(sqrtf(ss), 1e-12f);
    qn[t] = ln / n;
}

// ---------------- Kernel 2: cosine sim + per-block top-16 ------------------
__global__ __launch_bounds__(256) void sim_topk(
        const float* __restrict__ keys, const float* __restrict__ qn,
        float* __restrict__ cand_v, int* __restrict__ cand_i) {
    const int wid  = threadIdx.x >> 6;
    const int lane = threadIdx.x & 63;
    const int gw   = blockIdx.x * 4 + wid;       // global wave id
    const int GW   = NBLK2 * 4;

    const float4* q = (const float4*)qn;
    float4 q0 = q[lane], q1 = q[lane + 64];

    // wave-uniform top-16 (identical in all lanes -> no divergence, static idx)
    float v[16]; int id[16];
#pragma unroll
    for (int j = 0; j < 16; ++j) { v[j] = -FLT_MAX; id[j] = 0x7fffffff; }

    for (int r = gw; r < CAPACITY; r += GW) {
        const float4* k = (const float4*)(keys + (size_t)r * KEY_DIM);
        float4 k0 = k[lane], k1 = k[lane + 64];
        float dot = k0.x * q0.x + k0.y * q0.y + k0.z * q0.z + k0.w * q0.w
                  + k1.x * q1.x + k1.y * q1.y + k1.z * q1.z + k1.w * q1.w;
        float ss  = k0.x * k0.x + k0.y * k0.y + k0.z * k0.z + k0.w * k0.w
                  + k1.x * k1.x + k1.y * k1.y + k1.z * k1.z + k1.w * k1.w;
#pragma unroll
        for (int s = 32; s > 0; s >>= 1) {
            dot += __shfl_xor(dot, s);
            ss  += __shfl_xor(ss, s);
        }
        float sim = dot / fmaxf(sqrtf(ss), 1e-12f);
        if (sim > v[15]) {                       // wave-uniform branch
            float cv = sim; int ci = r;
#pragma unroll
            for (int j = 0; j < 16; ++j) {
                if (cv > v[j]) {
                    float tv = v[j]; int ti = id[j];
                    v[j] = cv; id[j] = ci; cv = tv; ci = ti;
                }
            }
        }
    }

    // merge 4 waves' top-16 -> block top-16
    __shared__ float bv[64];
    __shared__ int   bi[64];
    if (lane == 0) {
#pragma unroll
        for (int j = 0; j < 16; ++j) { bv[wid * 16 + j] = v[j]; bi[wid * 16 + j] = id[j]; }
    }
    __syncthreads();
    if (wid == 0) {
        float lv = bv[lane]; int li = bi[lane];
        for (int rr = 0; rr < NRET; ++rr) {
            float mv = lv; int mi = li;
#pragma unroll
            for (int s = 32; s > 0; s >>= 1) {
                float ov = __shfl_xor(mv, s); int oi = __shfl_xor(mi, s);
                if (ov > mv || (ov == mv && oi < mi)) { mv = ov; mi = oi; }
            }
            if (lane == 0) {
                cand_v[blockIdx.x * NRET + rr] = mv;
                cand_i[blockIdx.x * NRET + rr] = mi;
            }
            if (lv == mv && li == mi) { lv = -FLT_MAX; li = 0x7fffffff; }  // pop winner
        }
    }
}

// ---------------- Kernel 3: global top-16 + softmax + gather ---------------
__global__ __launch_bounds__(64) void merge_out(
        const float* __restrict__ cand_v, const int* __restrict__ cand_i,
        const float* __restrict__ values, float* __restrict__ out) {
    const int lane = threadIdx.x;                // 64 threads = 1 wave
    const int M = NBLK2 * NRET;

    float v[16]; int id[16];
#pragma unroll
    for (int j = 0; j < 16; ++j) { v[j] = -FLT_MAX; id[j] = 0x7fffffff; }

    for (int c = lane; c < M; c += 64) {
        float cv = cand_v[c]; int ci = cand_i[c];
        if (cv > v[15]) {
#pragma unroll
            for (int j = 0; j < 16; ++j) {
                if (cv > v[j]) {
                    float tv = v[j]; int ti = id[j];
                    v[j] = cv; id[j] = ci; cv = tv; ci = ti;
                }
            }
        }
    }

    // 16 rounds of wave argmax-pop; lane r keeps the r-th selected pair
    float sel_v = 0.f; int sel_i = 0;
    for (int rr = 0; rr < NRET; ++rr) {
        float mv = v[0]; int mi = id[0];
#pragma unroll
        for (int s = 32; s > 0; s >>= 1) {
            float ov = __shfl_xor(mv, s); int oi = __shfl_xor(mi, s);
            if (ov > mv || (ov == mv && oi < mi)) { mv = ov; mi = oi; }
        }
        if (v[0] == mv && id[0] == mi) {         // winner lane: shift head out
#pragma unroll
            for (int j = 0; j < 15; ++j) { v[j] = v[j + 1]; id[j] = id[j + 1]; }
            v[15] = -FLT_MAX; id[15] = 0x7fffffff;
        }
        if (lane == rr) { sel_v = mv; sel_i = mi; }
    }

    // softmax over the 16 (lane 0 holds the max since rounds are descending)
    float m0 = __shfl(sel_v, 0);
    float e = (lane < NRET) ? expf(sel_v - m0) : 0.0f;
    float denom = wave_sum(e);

    // out[d] = sum_r attn_r * values[idx_r, d];  lane covers d and d+64
    float acc0 = 0.f, acc1 = 0.f;
    for (int rr = 0; rr < NRET; ++rr) {
        float ar = __shfl(e, rr) / denom;
        int   ir = __shfl(sel_i, rr);
        const float* vr = values + (size_t)ir * VALUE_DIM;
        acc0 += ar * vr[lane];
        acc1 += ar * vr[lane + 64];
    }
    out[lane]      = acc0;
    out[lane + 64] = acc1;
}

extern "C" void kernel_launch(void* const* d_in, const int* in_sizes, int n_in,
                              void* d_out, int out_size, void* d_ws, size_t ws_size,
                              hipStream_t stream) {
    const float* query  = (const float*)d_in[0];
    const float* W1     = (const float*)d_in[1];
    const float* b1     = (const float*)d_in[2];
    const float* W2     = (const float*)d_in[3];
    const float* b2     = (const float*)d_in[4];
    const float* gamma  = (const float*)d_in[5];
    const float* beta   = (const float*)d_in[6];
    const float* keys   = (const float*)d_in[7];
    const float* values = (const float*)d_in[8];
    float* out = (float*)d_out;

    float* ws = (float*)d_ws;
    float* h1     = ws;                 // 512
    float* h2     = ws + 512;           // 512
    float* qn     = ws + 1024;          // 512
    float* cand_v = ws + 2048;          // NBLK2*16 floats
    int*   cand_i = (int*)(ws + 2048 + NBLK2 * NRET);

    matvec512<true ><<<128, 256, 0, stream>>>(W1, query, b1, h1);
    matvec512<false><<<128, 256, 0, stream>>>(W2, h1, b2, h2);
    ln_l2norm<<<1, 512, 0, stream>>>(h2, gamma, beta, qn);
    sim_topk<<<NBLK2, 256, 0, stream>>>(keys, qn, cand_v, cand_i);
    merge_out<<<1, 64, 0, stream>>>(cand_v, cand_i, values, out);
}

// Round 2
// 339.763 us; speedup vs baseline: 1.7894x; 1.7894x over previous
//
#include <hip/hip_runtime.h>
#include <hip/hip_bf16.h>
#include <float.h>
#include <math.h>

#define KEY_DIM   512
#define VALUE_DIM 128
#define CAPACITY  500000   // divisible by 4
#define NRET      16
#define NBLK2     1024     // blocks for the similarity kernel
#define ROWS_PER_ITER 4

__device__ __forceinline__ float wave_sum(float x) {
#pragma unroll
    for (int s = 32; s > 0; s >>= 1) x += __shfl_xor(x, s);
    return x;
}

// ---------------- Kernel 1a/1b: y[r] = act(dot(W[r,:], x) + b[r]) ----------
template <bool SILU>
__global__ __launch_bounds__(256) void matvec512(
        const float* __restrict__ W, const float* __restrict__ x,
        const float* __restrict__ b, float* __restrict__ y) {
    const int wid  = threadIdx.x >> 6;
    const int lane = threadIdx.x & 63;
    const int r = blockIdx.x * 4 + wid;          // 0..511

    const float4* Wr = (const float4*)(W + (size_t)r * KEY_DIM);
    const float4* xv = (const float4*)x;

    float4 w0 = Wr[lane], w1 = Wr[lane + 64];
    float4 x0 = xv[lane], x1 = xv[lane + 64];

    float dot = w0.x * x0.x + w0.y * x0.y + w0.z * x0.z + w0.w * x0.w
              + w1.x * x1.x + w1.y * x1.y + w1.z * x1.z + w1.w * x1.w;
    dot = wave_sum(dot);

    if (lane == 0) {
        float v = dot + b[r];
        if (SILU) v = v / (1.0f + expf(-v));     // silu = x*sigmoid(x)
        y[r] = v;
    }
}

// ---------------- Kernel 1c: LayerNorm + l2-normalize -> qn[512] -----------
__global__ __launch_bounds__(512) void ln_l2norm(
        const float* __restrict__ h, const float* __restrict__ gamma,
        const float* __restrict__ beta, float* __restrict__ qn) {
    __shared__ float s1[8], s2[8];
    const int t = threadIdx.x;                   // 512 threads = 8 waves
    const int wid = t >> 6, lane = t & 63;

    float x = h[t];
    float a = x, bb = x * x;
#pragma unroll
    for (int s = 32; s > 0; s >>= 1) { a += __shfl_xor(a, s); bb += __shfl_xor(bb, s); }
    if (lane == 0) { s1[wid] = a; s2[wid] = bb; }
    __syncthreads();

    float suma = 0.f, sumb = 0.f;
#pragma unroll
    for (int i = 0; i < 8; ++i) { suma += s1[i]; sumb += s2[i]; }
    float mu  = suma * (1.0f / KEY_DIM);
    float var = sumb * (1.0f / KEY_DIM) - mu * mu;      // biased, like torch LN
    float ln  = (x - mu) / sqrtf(var + 1e-5f) * gamma[t] + beta[t];

    float c = wave_sum(ln * ln);
    __syncthreads();
    if (lane == 0) s1[wid] = c;
    __syncthreads();
    float ss = 0.f;
#pragma unroll
    for (int i = 0; i < 8; ++i) ss += s1[i];
    float n = fmaxf(sqrtf(ss), 1e-12f);
    qn[t] = ln / n;
}

// ---------------- Kernel 2: cosine sim + per-block top-16 ------------------
// Each wave processes 4 CONTIGUOUS rows per iteration: 8 float4 loads issue
// back-to-back (4x memory-level parallelism vs 1-row version), and the 8
// butterfly reduction chains interleave for ILP.
__global__ __launch_bounds__(256) void sim_topk(
        const float* __restrict__ keys, const float* __restrict__ qn,
        float* __restrict__ cand_v, int* __restrict__ cand_i) {
    const int wid  = threadIdx.x >> 6;
    const int lane = threadIdx.x & 63;
    const int gw   = blockIdx.x * 4 + wid;       // global wave id
    const int GW   = NBLK2 * 4;

    const float4* q = (const float4*)qn;
    float4 q0 = q[lane], q1 = q[lane + 64];

    // wave-uniform top-16 (identical in all lanes -> no divergence, static idx)
    float v[16]; int id[16];
#pragma unroll
    for (int j = 0; j < 16; ++j) { v[j] = -FLT_MAX; id[j] = 0x7fffffff; }

    for (int base = gw * ROWS_PER_ITER; base < CAPACITY; base += GW * ROWS_PER_ITER) {
        float4 ka[ROWS_PER_ITER], kb[ROWS_PER_ITER];
#pragma unroll
        for (int j = 0; j < ROWS_PER_ITER; ++j) {
            const float4* kp = (const float4*)(keys + (size_t)(base + j) * KEY_DIM);
            ka[j] = kp[lane];
            kb[j] = kp[lane + 64];
        }
        float dot[ROWS_PER_ITER], ss[ROWS_PER_ITER];
#pragma unroll
        for (int j = 0; j < ROWS_PER_ITER; ++j) {
            dot[j] = ka[j].x * q0.x + ka[j].y * q0.y + ka[j].z * q0.z + ka[j].w * q0.w
                   + kb[j].x * q1.x + kb[j].y * q1.y + kb[j].z * q1.z + kb[j].w * q1.w;
            ss[j]  = ka[j].x * ka[j].x + ka[j].y * ka[j].y + ka[j].z * ka[j].z + ka[j].w * ka[j].w
                   + kb[j].x * kb[j].x + kb[j].y * kb[j].y + kb[j].z * kb[j].z + kb[j].w * kb[j].w;
        }
#pragma unroll
        for (int s = 32; s > 0; s >>= 1) {
#pragma unroll
            for (int j = 0; j < ROWS_PER_ITER; ++j) {
                dot[j] += __shfl_xor(dot[j], s);
                ss[j]  += __shfl_xor(ss[j], s);
            }
        }
#pragma unroll
        for (int j = 0; j < ROWS_PER_ITER; ++j) {
            float sim = dot[j] / fmaxf(sqrtf(ss[j]), 1e-12f);
            if (sim > v[15]) {                   // wave-uniform branch
                float cv = sim; int ci = base + j;
#pragma unroll
                for (int jj = 0; jj < 16; ++jj) {
                    if (cv > v[jj]) {
                        float tv = v[jj]; int ti = id[jj];
                        v[jj] = cv; id[jj] = ci; cv = tv; ci = ti;
                    }
                }
            }
        }
    }

    // merge 4 waves' top-16 -> block top-16
    __shared__ float bv[64];
    __shared__ int   bi[64];
    if (lane == 0) {
#pragma unroll
        for (int j = 0; j < 16; ++j) { bv[wid * 16 + j] = v[j]; bi[wid * 16 + j] = id[j]; }
    }
    __syncthreads();
    if (wid == 0) {
        float lv = bv[lane]; int li = bi[lane];
        for (int rr = 0; rr < NRET; ++rr) {
            float mv = lv; int mi = li;
#pragma unroll
            for (int s = 32; s > 0; s >>= 1) {
                float ov = __shfl_xor(mv, s); int oi = __shfl_xor(mi, s);
                if (ov > mv || (ov == mv && oi < mi)) { mv = ov; mi = oi; }
            }
            if (lane == 0) {
                cand_v[blockIdx.x * NRET + rr] = mv;
                cand_i[blockIdx.x * NRET + rr] = mi;
            }
            if (lv == mv && li == mi) { lv = -FLT_MAX; li = 0x7fffffff; }  // pop winner
        }
    }
}

// ---------------- Kernel 3: global top-16 + softmax + gather ---------------
// 256 threads: parallel scan (64 cands/lane, private top-16), per-wave
// argmax-pop -> LDS, wave 0 final pop + softmax + value gather.
__global__ __launch_bounds__(256) void merge_out(
        const float* __restrict__ cand_v, const int* __restrict__ cand_i,
        const float* __restrict__ values, float* __restrict__ out) {
    const int tid  = threadIdx.x;
    const int wid  = tid >> 6;
    const int lane = tid & 63;
    const int M = NBLK2 * NRET;                  // 16384

    float v[16]; int id[16];
#pragma unroll
    for (int j = 0; j < 16; ++j) { v[j] = -FLT_MAX; id[j] = 0x7fffffff; }

    for (int c = tid; c < M; c += 256) {         // 64 iterations
        float cv = cand_v[c]; int ci = cand_i[c];
        if (cv > v[15]) {                        // per-lane (divergent) insert
#pragma unroll
            for (int j = 0; j < 16; ++j) {
                if (cv > v[j]) {
                    float tv = v[j]; int ti = id[j];
                    v[j] = cv; id[j] = ci; cv = tv; ci = ti;
                }
            }
        }
    }

    // per-wave argmax-pop of 16 winners (heads are sorted per lane) -> LDS
    __shared__ float sv[64];
    __shared__ int   si[64];
    for (int rr = 0; rr < NRET; ++rr) {
        float mv = v[0]; int mi = id[0];
#pragma unroll
        for (int s = 32; s > 0; s >>= 1) {
            float ov = __shfl_xor(mv, s); int oi = __shfl_xor(mi, s);
            if (ov > mv || (ov == mv && oi < mi)) { mv = ov; mi = oi; }
        }
        if (v[0] == mv && id[0] == mi) {         // unique winner (unique indices)
#pragma unroll
            for (int j = 0; j < 15; ++j) { v[j] = v[j + 1]; id[j] = id[j + 1]; }
            v[15] = -FLT_MAX; id[15] = 0x7fffffff;
        }
        if (lane == 0) { sv[wid * 16 + rr] = mv; si[wid * 16 + rr] = mi; }
    }
    __syncthreads();

    if (wid == 0) {
        float lv = sv[lane]; int li = si[lane];
        float sel_v = -FLT_MAX; int sel_i = 0;
        for (int rr = 0; rr < NRET; ++rr) {
            float mv = lv; int mi = li;
#pragma unroll
            for (int s = 32; s > 0; s >>= 1) {
                float ov = __shfl_xor(mv, s); int oi = __shfl_xor(mi, s);
                if (ov > mv || (ov == mv && oi < mi)) { mv = ov; mi = oi; }
            }
            if (lv == mv && li == mi) { lv = -FLT_MAX; li = 0x7fffffff; }
            if (lane == rr) { sel_v = mv; sel_i = mi; }
        }

        // softmax over the 16 (lane 0 holds the max: rounds are descending)
        float m0 = __shfl(sel_v, 0);
        float e = (lane < NRET) ? expf(sel_v - m0) : 0.0f;
        float denom = wave_sum(e);

        float acc0 = 0.f, acc1 = 0.f;
        for (int rr = 0; rr < NRET; ++rr) {
            float ar = __shfl(e, rr) / denom;
            int   ir = __shfl(sel_i, rr);
            const float* vr = values + (size_t)ir * VALUE_DIM;
            acc0 += ar * vr[lane];
            acc1 += ar * vr[lane + 64];
        }
        out[lane]      = acc0;
        out[lane + 64] = acc1;
    }
}

extern "C" void kernel_launch(void* const* d_in, const int* in_sizes, int n_in,
                              void* d_out, int out_size, void* d_ws, size_t ws_size,
                              hipStream_t stream) {
    const float* query  = (const float*)d_in[0];
    const float* W1     = (const float*)d_in[1];
    const float* b1     = (const float*)d_in[2];
    const float* W2     = (const float*)d_in[3];
    const float* b2     = (const float*)d_in[4];
    const float* gamma  = (const float*)d_in[5];
    const float* beta   = (const float*)d_in[6];
    const float* keys   = (const float*)d_in[7];
    const float* values = (const float*)d_in[8];
    float* out = (float*)d_out;

    float* ws = (float*)d_ws;
    float* h1     = ws;                  // 512
    float* h2     = ws + 512;            // 512
    float* qn     = ws + 1024;           // 512
    float* cand_v = ws + 2048;           // NBLK2*16 floats
    int*   cand_i = (int*)(ws + 2048 + NBLK2 * NRET);

    matvec512<true ><<<128, 256, 0, stream>>>(W1, query, b1, h1);
    matvec512<false><<<128, 256, 0, stream>>>(W2, h1, b2, h2);
    ln_l2norm<<<1, 512, 0, stream>>>(h2, gamma, beta, qn);
    sim_topk<<<NBLK2, 256, 0, stream>>>(keys, qn, cand_v, cand_i);
    merge_out<<<1, 256, 0, stream>>>(cand_v, cand_i, values, out);
}